// Round 10
// baseline (881.749 us; speedup 1.0000x reference)
//
#include <hip/hip_runtime.h>
#include <cstdint>
#include <cstddef>
#include <math.h>

#define SEQ   2048
#define DIM   2048
#define NQKV  6144
#define NH    16
#define DH    128
#define ROWS  4096   /* b*n */

typedef unsigned short u16;
typedef unsigned int u32;
typedef __attribute__((ext_vector_type(8))) short bf16x8;
typedef __attribute__((ext_vector_type(4))) float f32x4;

__device__ __forceinline__ u16 f2bf(float f) {
  union { float f; u32 u; } v;
  v.f = f;
  u32 r = v.u + 0x7FFFu + ((v.u >> 16) & 1u);
  return (u16)(r >> 16);
}

// ------------------------------------------------ rmsnorm (fp64, 1 wave/row)
// [VERIFIED round 4 — do not touch]
__global__ __launch_bounds__(64) void rms_slow(
    const float* __restrict__ x, const float* __restrict__ g,
    float* __restrict__ xn) {
  int row = blockIdx.x, lane = threadIdx.x;
  const float* xr = x + (size_t)row * DIM;
  double ss = 0.0;
  for (int c = lane; c < DIM; c += 64) { double v = xr[c]; ss += v * v; }
  #pragma unroll
  for (int off = 32; off >= 1; off >>= 1) ss += __shfl_xor(ss, off);
  double nrm = sqrt(ss); if (nrm < 1e-12) nrm = 1e-12;
  double sc = 45.254833995939045 / nrm;   // sqrt(2048)/||x||
  float* dst = xn + (size_t)row * DIM;
  for (int c = lane; c < DIM; c += 64) dst[c] = (float)((double)xr[c] * sc * (double)g[c]);
}

// ------------------------- bf16 MFMA NN GEMM, A fp32-cast or native bf16 ----
// [VERIFIED rounds 5/6 — unchanged]
template <typename AT>
__global__ __launch_bounds__(256) void gemm_nn(
    const AT* __restrict__ A, const float* __restrict__ B,
    float* __restrict__ C, int M, int N, int K) {
  __shared__ u16 As[128 * 40];   // [m][k]
  __shared__ u16 Bs[128 * 40];   // [n][k]
  int bm = blockIdx.x * 128;
  int bn = blockIdx.y * 128;
  int tid = threadIdx.x;
  int wid = tid >> 6, lane = tid & 63;
  int wr = wid >> 1, wc = wid & 1;
  int fr = lane & 15, fq = lane >> 4;

  int ar = tid >> 1;
  int ak = (tid & 1) * 16;
  int bn_t = tid & 127;
  int bk_t = tid >> 7;

  f32x4 acc[4][4] = {};

  const u16* a_rd = As + (wr * 64 + fr) * 40 + fq * 8;
  const u16* b_rd = Bs + (wc * 64 + fr) * 40 + fq * 8;

  for (int k0 = 0; k0 < K; k0 += 32) {
    int4 aq0, aq1;
    if constexpr (sizeof(AT) == 4) {
      const float4* ap = (const float4*)(A + (size_t)(bm + ar) * K + k0 + ak);
      float4 a0 = ap[0], a1 = ap[1], a2 = ap[2], a3 = ap[3];
      union { u16 h[16]; int4 q[2]; } cv;
      cv.h[0]=f2bf(a0.x); cv.h[1]=f2bf(a0.y); cv.h[2]=f2bf(a0.z); cv.h[3]=f2bf(a0.w);
      cv.h[4]=f2bf(a1.x); cv.h[5]=f2bf(a1.y); cv.h[6]=f2bf(a1.z); cv.h[7]=f2bf(a1.w);
      cv.h[8]=f2bf(a2.x); cv.h[9]=f2bf(a2.y); cv.h[10]=f2bf(a2.z); cv.h[11]=f2bf(a2.w);
      cv.h[12]=f2bf(a3.x); cv.h[13]=f2bf(a3.y); cv.h[14]=f2bf(a3.z); cv.h[15]=f2bf(a3.w);
      aq0 = cv.q[0]; aq1 = cv.q[1];
    } else {
      const int4* ap = (const int4*)(A + (size_t)(bm + ar) * K + k0 + ak);
      aq0 = ap[0]; aq1 = ap[1];
    }
    float breg[16];
    #pragma unroll
    for (int it = 0; it < 16; ++it)
      breg[it] = B[(size_t)(k0 + bk_t + it * 2) * N + bn + bn_t];

    __syncthreads();
    *(int4*)(As + ar * 40 + ak) = aq0;
    *(int4*)(As + ar * 40 + ak + 8) = aq1;
    #pragma unroll
    for (int it = 0; it < 16; ++it)
      Bs[bn_t * 40 + bk_t + it * 2] = f2bf(breg[it]);
    __syncthreads();

    bf16x8 af[4], bfr[4];
    #pragma unroll
    for (int m = 0; m < 4; ++m) af[m]  = *(const bf16x8*)(a_rd + m * 16 * 40);
    #pragma unroll
    for (int n = 0; n < 4; ++n) bfr[n] = *(const bf16x8*)(b_rd + n * 16 * 40);
    #pragma unroll
    for (int m = 0; m < 4; ++m)
      #pragma unroll
      for (int n = 0; n < 4; ++n)
        acc[m][n] = __builtin_amdgcn_mfma_f32_16x16x32_bf16(af[m], bfr[n], acc[m][n], 0, 0, 0);
  }
  #pragma unroll
  for (int m = 0; m < 4; ++m)
    #pragma unroll
    for (int n = 0; n < 4; ++n)
      #pragma unroll
      for (int r = 0; r < 4; ++r) {
        int row = bm + wr * 64 + m * 16 + fq * 4 + r;
        int col = bn + wc * 64 + n * 16 + fr;
        C[(size_t)row * N + col] = acc[m][n][r];
      }
}

// ---------------------------------- cached_kv: one thread per output element
// [VERIFIED round 4 — do not touch]
__global__ __launch_bounds__(256) void kvout_slow(
    const float* __restrict__ qkv, float* __restrict__ cached) {
  size_t gid = (size_t)blockIdx.x * 256 + threadIdx.x;  // 16,777,216
  int d = (int)(gid & 127);
  size_t r = gid >> 7;
  int n = (int)(r & 2047); r >>= 11;
  int h = (int)(r & 15);   r >>= 4;
  int b = (int)(r & 1);    r >>= 1;
  int kv = (int)r;         // 0=k, 1=v  (pre-RoPE)
  cached[gid] = qkv[(size_t)(b * SEQ + n) * NQKV + (size_t)(1 + kv) * DIM + h * DH + d];
}

// ------------------------- RoPE cos/sin table (fp64 build, fp32 store) ------
// table[n*64 + p] = {cos, sin} of n * 10000^(-p/64) — same fp64 math as the
// verified rope_slow, computed once per (n,p) instead of 64x redundantly.
__global__ __launch_bounds__(256) void rope_table(float2* __restrict__ tab) {
  int gid = blockIdx.x * 256 + threadIdx.x;   // 131072
  int p = gid & 63;
  int n = gid >> 6;
  double inv = pow(10000.0, -(double)p / 64.0);
  double ang = (double)n * inv;
  tab[gid] = make_float2((float)cos(ang), (float)sin(ang));
}

// ------------------------------------- RoPE apply in-place (fp32, per pair) -
// Index decomposition identical to verified rope_slow; trig values from table.
__global__ __launch_bounds__(256) void rope_apply(float* __restrict__ qkv,
                                                  const float2* __restrict__ tab) {
  int gid = blockIdx.x * 256 + threadIdx.x;   // 8,388,608 pairs (q and k)
  int p = gid & 63;
  int n = (gid >> 6) & 2047;
  int h = (gid >> 17) & 15;
  int s = (gid >> 21) & 1;    // 0 = q, 1 = k
  int b = (gid >> 22) & 1;
  float* base = qkv + (size_t)(b * SEQ + n) * NQKV + s * DIM + h * DH + 2 * p;
  float2 cs = tab[n * 64 + p];
  float2 w = *(float2*)base;
  float2 o;
  o.x = w.x * cs.x - w.y * cs.y;
  o.y = w.y * cs.x + w.x * cs.y;
  *(float2*)base = o;
}

// ------------------------- V transpose + cast -> vT[bh][d][n] (bf16) --------
// [VERIFIED round 6 — unchanged]
__global__ void transpose_v_cast(const float* __restrict__ qkv,
                                 u16* __restrict__ vT) {
  int bh = blockIdx.z; int b = bh >> 4, h = bh & 15;
  int d0 = blockIdx.x * 32, n0 = blockIdx.y * 32;
  __shared__ float tile[32][33];
  int tx = threadIdx.x, ty = threadIdx.y;   // (32,8)
  const float* src = qkv + (size_t)(b * SEQ + n0) * NQKV + 2 * DIM + h * DH + d0;
  #pragma unroll
  for (int j = 0; j < 32; j += 8)
    tile[ty + j][tx] = src[(size_t)(ty + j) * NQKV + tx];
  __syncthreads();
  u16* dst = vT + ((size_t)bh * DH + d0) * SEQ + n0;
  #pragma unroll
  for (int j = 0; j < 32; j += 8)
    dst[(size_t)(ty + j) * SEQ + tx] = f2bf(tile[tx][ty + j]);
}

// ----------------- pack post-RoPE q,k as bf16 into the dead fp32-V region ---
// [VERIFIED round 7 — unchanged]
__global__ __launch_bounds__(256) void pack_qk(float* __restrict__ qkv) {
  int row = blockIdx.x;           // 0..4095
  int t = threadIdx.x;            // 16 elems each over q+k (4096 elems)
  const float* src = qkv + (size_t)row * NQKV + t * 16;
  float4 f0 = ((const float4*)src)[0];
  float4 f1 = ((const float4*)src)[1];
  float4 f2 = ((const float4*)src)[2];
  float4 f3 = ((const float4*)src)[3];
  union { u16 h[16]; int4 q[2]; } cv;
  cv.h[0]=f2bf(f0.x);  cv.h[1]=f2bf(f0.y);  cv.h[2]=f2bf(f0.z);  cv.h[3]=f2bf(f0.w);
  cv.h[4]=f2bf(f1.x);  cv.h[5]=f2bf(f1.y);  cv.h[6]=f2bf(f1.z);  cv.h[7]=f2bf(f1.w);
  cv.h[8]=f2bf(f2.x);  cv.h[9]=f2bf(f2.y);  cv.h[10]=f2bf(f2.z); cv.h[11]=f2bf(f2.w);
  cv.h[12]=f2bf(f3.x); cv.h[13]=f2bf(f3.y); cv.h[14]=f2bf(f3.z); cv.h[15]=f2bf(f3.w);
  u16* dst = (u16*)(qkv + (size_t)row * NQKV) + 8192 + t * 16;
  ((int4*)dst)[0] = cv.q[0];
  ((int4*)dst)[1] = cv.q[1];
}

// --------------- MFMA causal flash attention, 4 waves x 16 q-rows / block ---
// Per-wave tile math byte-identical to round 9 (K-reg prefetch, V hoist).
// 256-thread workgroups restore wave residency (round-9 post-mortem: 64-thr
// workgroups capped occupancy at ~2.4 waves/CU via workgroup slots, not VGPR).
// No barriers: each wave owns its P_lds slice; waves drift for MFMA/VALU
// co-scheduling (m114). s_setprio around MFMA clusters (T5).
__global__ __launch_bounds__(256) void attn_mfma4w(
    const u16* __restrict__ qkp,   // u16 view of qkvf (packed q,k in V region)
    const u16* __restrict__ vT,    // (32,128,2048) bf16
    u16* __restrict__ ctx) {       // (4096, 2048) bf16
  int qt = 31 - blockIdx.x;        // 64-row block tile, longest first
  int bh = blockIdx.y;             // 0..31
  int b = bh >> 4, h = bh & 15;
  int tid = threadIdx.x;
  int wid = tid >> 6, lane = tid & 63;
  int fr = lane & 15, fq = lane >> 4;
  int qr0 = qt * 64 + wid * 16;

  __shared__ u16 P_lds[4][16 * 72];
  u16* Pw = &P_lds[wid][0];

  const size_t rstr = 2 * NQKV;    // u16 per row
  const u16* Qb = qkp + (size_t)(b * SEQ) * rstr + 8192 + h * 128;
  const u16* Kb = qkp + (size_t)(b * SEQ) * rstr + 10240 + h * 128;
  const u16* Vt = vT + (size_t)bh * DH * SEQ;

  bf16x8 qf[4];
  {
    const u16* qrow = Qb + (size_t)(qr0 + fr) * rstr + fq * 8;
    #pragma unroll
    for (int kk = 0; kk < 4; ++kk) qf[kk] = *(const bf16x8*)(qrow + kk * 32);
  }

  f32x4 acc[8] = {};
  float m_r[4], l_r[4];
  #pragma unroll
  for (int r = 0; r < 4; ++r) { m_r[r] = -3e38f; l_r[r] = 0.f; }

  const float scale = 0.08838834764831845f;
  int i0 = qr0 + fq * 4;
  int jt_end = qt;                 // (qr0+15)>>6 == qt for all 4 waves

  bf16x8 kreg[16];   // [jf][kk]
  bf16x8 vreg[16];   // [df][half]

  // preload K tile 0
  #pragma unroll
  for (int jf = 0; jf < 4; ++jf) {
    const u16* krow = Kb + (size_t)(jf * 16 + fr) * rstr + fq * 8;
    #pragma unroll
    for (int kk = 0; kk < 4; ++kk) kreg[jf * 4 + kk] = *(const bf16x8*)(krow + kk * 32);
  }

  for (int jt = 0; jt <= jt_end; ++jt) {
    int j0 = jt * 64;

    // issue V loads for THIS tile now — consumed after softmax
    #pragma unroll
    for (int df = 0; df < 8; ++df) {
      const u16* vrow = Vt + (size_t)(df * 16 + fr) * SEQ + j0 + fq * 8;
      vreg[df * 2]     = *(const bf16x8*)(vrow);
      vreg[df * 2 + 1] = *(const bf16x8*)(vrow + 32);
    }

    // QK^T from register-resident K
    f32x4 s[4];
    __builtin_amdgcn_s_setprio(1);
    #pragma unroll
    for (int jf = 0; jf < 4; ++jf) {
      f32x4 sa = {0.f, 0.f, 0.f, 0.f};
      #pragma unroll
      for (int kk = 0; kk < 4; ++kk)
        sa = __builtin_amdgcn_mfma_f32_16x16x32_bf16(qf[kk], kreg[jf * 4 + kk], sa, 0, 0, 0);
      s[jf] = sa;
    }
    __builtin_amdgcn_s_setprio(0);

    // prefetch NEXT K tile into the same (now dead) registers
    if (jt < jt_end) {
      int jn0 = j0 + 64;
      #pragma unroll
      for (int jf = 0; jf < 4; ++jf) {
        const u16* krow = Kb + (size_t)(jn0 + jf * 16 + fr) * rstr + fq * 8;
        #pragma unroll
        for (int kk = 0; kk < 4; ++kk) kreg[jf * 4 + kk] = *(const bf16x8*)(krow + kk * 32);
      }
    }

    #pragma unroll
    for (int jf = 0; jf < 4; ++jf) {
      int j = j0 + jf * 16 + fr;
      #pragma unroll
      for (int r = 0; r < 4; ++r) {
        float v = s[jf][r] * scale;
        s[jf][r] = (j > i0 + r) ? -1e30f : v;
      }
    }
    float al[4], ls[4];
    #pragma unroll
    for (int r = 0; r < 4; ++r) {
      float mx = fmaxf(fmaxf(s[0][r], s[1][r]), fmaxf(s[2][r], s[3][r]));
      #pragma unroll
      for (int off = 8; off >= 1; off >>= 1) mx = fmaxf(mx, __shfl_xor(mx, off));
      float mn = fmaxf(m_r[r], mx);
      al[r] = __expf(m_r[r] - mn);
      m_r[r] = mn;
      float sum = 0.f;
      #pragma unroll
      for (int jf = 0; jf < 4; ++jf) {
        float p = __expf(s[jf][r] - mn);
        s[jf][r] = p;
        sum += p;
      }
      #pragma unroll
      for (int off = 8; off >= 1; off >>= 1) sum += __shfl_xor(sum, off);
      ls[r] = sum;
    }
    #pragma unroll
    for (int jf = 0; jf < 4; ++jf)
      #pragma unroll
      for (int r = 0; r < 4; ++r)
        Pw[(fq * 4 + r) * 72 + jf * 16 + fr] = f2bf(s[jf][r]);
    #pragma unroll
    for (int r = 0; r < 4; ++r) l_r[r] = l_r[r] * al[r] + ls[r];
    #pragma unroll
    for (int df = 0; df < 8; ++df)
      #pragma unroll
      for (int r = 0; r < 4; ++r) acc[df][r] *= al[r];

    bf16x8 pa0 = *(const bf16x8*)(Pw + fr * 72 + fq * 8);
    bf16x8 pa1 = *(const bf16x8*)(Pw + fr * 72 + 32 + fq * 8);
    __builtin_amdgcn_s_setprio(1);
    #pragma unroll
    for (int df = 0; df < 8; ++df) {
      acc[df] = __builtin_amdgcn_mfma_f32_16x16x32_bf16(pa0, vreg[df * 2],     acc[df], 0, 0, 0);
      acc[df] = __builtin_amdgcn_mfma_f32_16x16x32_bf16(pa1, vreg[df * 2 + 1], acc[df], 0, 0, 0);
    }
    __builtin_amdgcn_s_setprio(0);
  }
  #pragma unroll
  for (int df = 0; df < 8; ++df)
    #pragma unroll
    for (int r = 0; r < 4; ++r) {
      int i = qr0 + fq * 4 + r;
      int d = df * 16 + fr;
      ctx[(size_t)(b * SEQ + i) * DIM + h * DH + d] = f2bf(acc[df][r] / l_r[r]);
    }
}

// ----------------------------------------------------------------- launch ---
extern "C" void kernel_launch(void* const* d_in, const int* in_sizes, int n_in,
                              void* d_out, int out_size, void* d_ws, size_t ws_size,
                              hipStream_t stream) {
  // size-keyed input selection (sizes are pairwise distinct)
  const float *x = nullptr, *gamma = nullptr, *wq = nullptr, *wo = nullptr;
  for (int ii = 0; ii < n_in; ++ii) {
    switch (in_sizes[ii]) {
      case  8388608: x     = (const float*)d_in[ii]; break;
      case     2048: gamma = (const float*)d_in[ii]; break;
      case 12582912: wq    = (const float*)d_in[ii]; break;
      case  4194304: wo    = (const float*)d_in[ii]; break;
    }
  }
  if (!x || !gamma || !wq || !wo) {   // fallback: documented dict order
    x = (const float*)d_in[0]; gamma = (const float*)d_in[1];
    wq = (const float*)d_in[2]; wo = (const float*)d_in[3];
  }

  float* out    = (float*)d_out;           // (2,2048,2048)
  float* cached = out + 8388608;           // (2,2,16,2048,128)

  // ws (134.2 MB, proven footprint):
  //   [0, 33.55MB)      xn (fp32) — dead after QKV GEMM; then reused as:
  //       [0, 16.78MB)      ctx (bf16)
  //       [16.78, 33.55MB)  vT  (bf16)
  //   [33.55, 134.2MB)  qkv (fp32; V third repurposed for packed bf16 q,k)
  // rope table (1 MB) lives in the head of `out`, which the final GEMM
  // fully overwrites afterwards — deterministic across replays.
  float* xn   = (float*)d_ws;
  u16*   ctx  = (u16*)d_ws;
  u16*   vT   = ctx + (size_t)ROWS * DIM;
  float* qkvf = (float*)((char*)d_ws + (size_t)ROWS * DIM * 4);
  float2* tab = (float2*)d_out;            // 2048*64*8B = 1 MB scratch

  rms_slow<<<ROWS, 64, 0, stream>>>(x, gamma, xn);
  rope_table<<<131072 / 256, 256, 0, stream>>>(tab);
  gemm_nn<float><<<dim3(ROWS / 128, NQKV / 128), 256, 0, stream>>>(xn, wq, qkvf, ROWS, NQKV, DIM);
  kvout_slow<<<65536, 256, 0, stream>>>(qkvf, cached);
  rope_apply<<<32768, 256, 0, stream>>>(qkvf, tab);
  transpose_v_cast<<<dim3(DH / 32, SEQ / 32, 32), dim3(32, 8), 0, stream>>>(qkvf, vT);
  pack_qk<<<ROWS, 256, 0, stream>>>(qkvf);
  attn_mfma4w<<<dim3(32, 32), 256, 0, stream>>>((const u16*)qkvf, vT, ctx);
  gemm_nn<u16><<<dim3(ROWS / 128, DIM / 128), 256, 0, stream>>>(ctx, wo, out, ROWS, DIM, DIM);
}

// Round 11
// 678.242 us; speedup vs baseline: 1.3001x; 1.3001x over previous
//
#include <hip/hip_runtime.h>
#include <cstdint>
#include <cstddef>
#include <math.h>

#define SEQ   2048
#define DIM   2048
#define NQKV  6144
#define NH    16
#define DH    128
#define ROWS  4096   /* b*n */

typedef unsigned short u16;
typedef unsigned int u32;
typedef __attribute__((ext_vector_type(8))) short bf16x8;
typedef __attribute__((ext_vector_type(4))) float f32x4;

__device__ __forceinline__ u16 f2bf(float f) {
  union { float f; u32 u; } v;
  v.f = f;
  u32 r = v.u + 0x7FFFu + ((v.u >> 16) & 1u);
  return (u16)(r >> 16);
}

// ------------------------------------------------ rmsnorm (fp64, 1 wave/row)
// [VERIFIED round 4 — do not touch]
__global__ __launch_bounds__(64) void rms_slow(
    const float* __restrict__ x, const float* __restrict__ g,
    float* __restrict__ xn) {
  int row = blockIdx.x, lane = threadIdx.x;
  const float* xr = x + (size_t)row * DIM;
  double ss = 0.0;
  for (int c = lane; c < DIM; c += 64) { double v = xr[c]; ss += v * v; }
  #pragma unroll
  for (int off = 32; off >= 1; off >>= 1) ss += __shfl_xor(ss, off);
  double nrm = sqrt(ss); if (nrm < 1e-12) nrm = 1e-12;
  double sc = 45.254833995939045 / nrm;   // sqrt(2048)/||x||
  float* dst = xn + (size_t)row * DIM;
  for (int c = lane; c < DIM; c += 64) dst[c] = (float)((double)xr[c] * sc * (double)g[c]);
}

// ------------------------- bf16 MFMA NN GEMM, A fp32-cast or native bf16 ----
// [VERIFIED rounds 5/6 — unchanged]
template <typename AT>
__global__ __launch_bounds__(256) void gemm_nn(
    const AT* __restrict__ A, const float* __restrict__ B,
    float* __restrict__ C, int M, int N, int K) {
  __shared__ u16 As[128 * 40];   // [m][k]
  __shared__ u16 Bs[128 * 40];   // [n][k]
  int bm = blockIdx.x * 128;
  int bn = blockIdx.y * 128;
  int tid = threadIdx.x;
  int wid = tid >> 6, lane = tid & 63;
  int wr = wid >> 1, wc = wid & 1;
  int fr = lane & 15, fq = lane >> 4;

  int ar = tid >> 1;
  int ak = (tid & 1) * 16;
  int bn_t = tid & 127;
  int bk_t = tid >> 7;

  f32x4 acc[4][4] = {};

  const u16* a_rd = As + (wr * 64 + fr) * 40 + fq * 8;
  const u16* b_rd = Bs + (wc * 64 + fr) * 40 + fq * 8;

  for (int k0 = 0; k0 < K; k0 += 32) {
    int4 aq0, aq1;
    if constexpr (sizeof(AT) == 4) {
      const float4* ap = (const float4*)(A + (size_t)(bm + ar) * K + k0 + ak);
      float4 a0 = ap[0], a1 = ap[1], a2 = ap[2], a3 = ap[3];
      union { u16 h[16]; int4 q[2]; } cv;
      cv.h[0]=f2bf(a0.x); cv.h[1]=f2bf(a0.y); cv.h[2]=f2bf(a0.z); cv.h[3]=f2bf(a0.w);
      cv.h[4]=f2bf(a1.x); cv.h[5]=f2bf(a1.y); cv.h[6]=f2bf(a1.z); cv.h[7]=f2bf(a1.w);
      cv.h[8]=f2bf(a2.x); cv.h[9]=f2bf(a2.y); cv.h[10]=f2bf(a2.z); cv.h[11]=f2bf(a2.w);
      cv.h[12]=f2bf(a3.x); cv.h[13]=f2bf(a3.y); cv.h[14]=f2bf(a3.z); cv.h[15]=f2bf(a3.w);
      aq0 = cv.q[0]; aq1 = cv.q[1];
    } else {
      const int4* ap = (const int4*)(A + (size_t)(bm + ar) * K + k0 + ak);
      aq0 = ap[0]; aq1 = ap[1];
    }
    float breg[16];
    #pragma unroll
    for (int it = 0; it < 16; ++it)
      breg[it] = B[(size_t)(k0 + bk_t + it * 2) * N + bn + bn_t];

    __syncthreads();
    *(int4*)(As + ar * 40 + ak) = aq0;
    *(int4*)(As + ar * 40 + ak + 8) = aq1;
    #pragma unroll
    for (int it = 0; it < 16; ++it)
      Bs[bn_t * 40 + bk_t + it * 2] = f2bf(breg[it]);
    __syncthreads();

    bf16x8 af[4], bfr[4];
    #pragma unroll
    for (int m = 0; m < 4; ++m) af[m]  = *(const bf16x8*)(a_rd + m * 16 * 40);
    #pragma unroll
    for (int n = 0; n < 4; ++n) bfr[n] = *(const bf16x8*)(b_rd + n * 16 * 40);
    #pragma unroll
    for (int m = 0; m < 4; ++m)
      #pragma unroll
      for (int n = 0; n < 4; ++n)
        acc[m][n] = __builtin_amdgcn_mfma_f32_16x16x32_bf16(af[m], bfr[n], acc[m][n], 0, 0, 0);
  }
  #pragma unroll
  for (int m = 0; m < 4; ++m)
    #pragma unroll
    for (int n = 0; n < 4; ++n)
      #pragma unroll
      for (int r = 0; r < 4; ++r) {
        int row = bm + wr * 64 + m * 16 + fq * 4 + r;
        int col = bn + wc * 64 + n * 16 + fr;
        C[(size_t)row * N + col] = acc[m][n][r];
      }
}

// ---------------------------------- cached_kv: one thread per output element
// [VERIFIED round 4 — do not touch]
__global__ __launch_bounds__(256) void kvout_slow(
    const float* __restrict__ qkv, float* __restrict__ cached) {
  size_t gid = (size_t)blockIdx.x * 256 + threadIdx.x;  // 16,777,216
  int d = (int)(gid & 127);
  size_t r = gid >> 7;
  int n = (int)(r & 2047); r >>= 11;
  int h = (int)(r & 15);   r >>= 4;
  int b = (int)(r & 1);    r >>= 1;
  int kv = (int)r;         // 0=k, 1=v  (pre-RoPE)
  cached[gid] = qkv[(size_t)(b * SEQ + n) * NQKV + (size_t)(1 + kv) * DIM + h * DH + d];
}

// ------------------------- RoPE cos/sin table (fp64 build, fp32 store) ------
// [VERIFIED round 10 — unchanged]
__global__ __launch_bounds__(256) void rope_table(float2* __restrict__ tab) {
  int gid = blockIdx.x * 256 + threadIdx.x;   // 131072
  int p = gid & 63;
  int n = gid >> 6;
  double inv = pow(10000.0, -(double)p / 64.0);
  double ang = (double)n * inv;
  tab[gid] = make_float2((float)cos(ang), (float)sin(ang));
}

// ------------------------------------- RoPE apply in-place (fp32, per pair) -
// [VERIFIED round 10 — unchanged]
__global__ __launch_bounds__(256) void rope_apply(float* __restrict__ qkv,
                                                  const float2* __restrict__ tab) {
  int gid = blockIdx.x * 256 + threadIdx.x;   // 8,388,608 pairs (q and k)
  int p = gid & 63;
  int n = (gid >> 6) & 2047;
  int h = (gid >> 17) & 15;
  int s = (gid >> 21) & 1;    // 0 = q, 1 = k
  int b = (gid >> 22) & 1;
  float* base = qkv + (size_t)(b * SEQ + n) * NQKV + s * DIM + h * DH + 2 * p;
  float2 cs = tab[n * 64 + p];
  float2 w = *(float2*)base;
  float2 o;
  o.x = w.x * cs.x - w.y * cs.y;
  o.y = w.y * cs.x + w.x * cs.y;
  *(float2*)base = o;
}

// ------------------------- V transpose + cast -> vT[bh][d][n] (bf16) --------
// [VERIFIED round 6 — unchanged]
__global__ void transpose_v_cast(const float* __restrict__ qkv,
                                 u16* __restrict__ vT) {
  int bh = blockIdx.z; int b = bh >> 4, h = bh & 15;
  int d0 = blockIdx.x * 32, n0 = blockIdx.y * 32;
  __shared__ float tile[32][33];
  int tx = threadIdx.x, ty = threadIdx.y;   // (32,8)
  const float* src = qkv + (size_t)(b * SEQ + n0) * NQKV + 2 * DIM + h * DH + d0;
  #pragma unroll
  for (int j = 0; j < 32; j += 8)
    tile[ty + j][tx] = src[(size_t)(ty + j) * NQKV + tx];
  __syncthreads();
  u16* dst = vT + ((size_t)bh * DH + d0) * SEQ + n0;
  #pragma unroll
  for (int j = 0; j < 32; j += 8)
    dst[(size_t)(ty + j) * SEQ + tx] = f2bf(tile[tx][ty + j]);
}

// ----------------- pack post-RoPE q,k as bf16 into the dead fp32-V region ---
// [VERIFIED round 7 — unchanged]
__global__ __launch_bounds__(256) void pack_qk(float* __restrict__ qkv) {
  int row = blockIdx.x;           // 0..4095
  int t = threadIdx.x;            // 16 elems each over q+k (4096 elems)
  const float* src = qkv + (size_t)row * NQKV + t * 16;
  float4 f0 = ((const float4*)src)[0];
  float4 f1 = ((const float4*)src)[1];
  float4 f2 = ((const float4*)src)[2];
  float4 f3 = ((const float4*)src)[3];
  union { u16 h[16]; int4 q[2]; } cv;
  cv.h[0]=f2bf(f0.x);  cv.h[1]=f2bf(f0.y);  cv.h[2]=f2bf(f0.z);  cv.h[3]=f2bf(f0.w);
  cv.h[4]=f2bf(f1.x);  cv.h[5]=f2bf(f1.y);  cv.h[6]=f2bf(f1.z);  cv.h[7]=f2bf(f1.w);
  cv.h[8]=f2bf(f2.x);  cv.h[9]=f2bf(f2.y);  cv.h[10]=f2bf(f2.z); cv.h[11]=f2bf(f2.w);
  cv.h[12]=f2bf(f3.x); cv.h[13]=f2bf(f3.y); cv.h[14]=f2bf(f3.z); cv.h[15]=f2bf(f3.w);
  u16* dst = (u16*)(qkv + (size_t)row * NQKV) + 8192 + t * 16;
  ((int4*)dst)[0] = cv.q[0];
  ((int4*)dst)[1] = cv.q[1];
}

// --------------------- MFMA causal flash attention, 1 wave / 16 q-rows ------
// Tile body byte-identical to round 9 (K-reg prefetch one tile ahead, V loads
// hoisted above softmax). ONLY the blockIdx decode changed: XCD-sequential bh
// ownership (T1). Round-10 diagnosis: FETCH_SIZE 160 MB/dispatch — K/V of
// every bh re-fetched from HBM because consecutive blocks round-robin across
// the 8 per-XCD L2s. Mapping: wg = ((bh>>3)*128 + (127-qt))*8 + (bh&7), so
// XCD x (= wg&7) processes bh = x, 8+x, 16+x, 24+x sequentially, longest qt
// first; live working set/XCD = one bh ~ 1.5 MB << 4 MB L2.
__global__ __launch_bounds__(64) void attn_mfma16(
    const u16* __restrict__ qkp,   // u16 view of qkvf (packed q,k in V region)
    const u16* __restrict__ vT,    // (32,128,2048) bf16
    u16* __restrict__ ctx) {       // (4096, 2048) bf16
  int wg = blockIdx.x;             // 0..4095
  int xcd = wg & 7;
  int g   = wg >> 3;               // 0..511 within-XCD sequence
  int bh  = (g >> 7) * 8 + xcd;    // 0..31
  int qt  = 127 - (g & 127);       // longest blocks first within each bh
  int b = bh >> 4, h = bh & 15;
  int lane = threadIdx.x;
  int fr = lane & 15, fq = lane >> 4;
  int qr0 = qt * 16;

  __shared__ u16 Pw[16 * 72];

  const size_t rstr = 2 * NQKV;    // u16 per row
  const u16* Qb = qkp + (size_t)(b * SEQ) * rstr + 8192 + h * 128;
  const u16* Kb = qkp + (size_t)(b * SEQ) * rstr + 10240 + h * 128;
  const u16* Vt = vT + (size_t)bh * DH * SEQ;

  bf16x8 qf[4];
  {
    const u16* qrow = Qb + (size_t)(qr0 + fr) * rstr + fq * 8;
    #pragma unroll
    for (int kk = 0; kk < 4; ++kk) qf[kk] = *(const bf16x8*)(qrow + kk * 32);
  }

  f32x4 acc[8] = {};
  float m_r[4], l_r[4];
  #pragma unroll
  for (int r = 0; r < 4; ++r) { m_r[r] = -3e38f; l_r[r] = 0.f; }

  const float scale = 0.08838834764831845f;
  int i0 = qr0 + fq * 4;
  int jt_end = qt >> 2;

  // register-resident K and V tiles
  bf16x8 kreg[16];   // [jf][kk]
  bf16x8 vreg[16];   // [df][half]

  // preload K tile 0
  #pragma unroll
  for (int jf = 0; jf < 4; ++jf) {
    const u16* krow = Kb + (size_t)(jf * 16 + fr) * rstr + fq * 8;
    #pragma unroll
    for (int kk = 0; kk < 4; ++kk) kreg[jf * 4 + kk] = *(const bf16x8*)(krow + kk * 32);
  }

  for (int jt = 0; jt <= jt_end; ++jt) {
    int j0 = jt * 64;

    // issue V loads for THIS tile now — consumed after softmax (~1k cy later)
    #pragma unroll
    for (int df = 0; df < 8; ++df) {
      const u16* vrow = Vt + (size_t)(df * 16 + fr) * SEQ + j0 + fq * 8;
      vreg[df * 2]     = *(const bf16x8*)(vrow);
      vreg[df * 2 + 1] = *(const bf16x8*)(vrow + 32);
    }

    // QK^T from register-resident K
    f32x4 s[4];
    #pragma unroll
    for (int jf = 0; jf < 4; ++jf) {
      f32x4 sa = {0.f, 0.f, 0.f, 0.f};
      #pragma unroll
      for (int kk = 0; kk < 4; ++kk)
        sa = __builtin_amdgcn_mfma_f32_16x16x32_bf16(qf[kk], kreg[jf * 4 + kk], sa, 0, 0, 0);
      s[jf] = sa;
    }

    // prefetch NEXT K tile into the same (now dead) registers;
    // refill latency hides under mask+softmax+P below.
    if (jt < jt_end) {
      int jn0 = j0 + 64;
      #pragma unroll
      for (int jf = 0; jf < 4; ++jf) {
        const u16* krow = Kb + (size_t)(jn0 + jf * 16 + fr) * rstr + fq * 8;
        #pragma unroll
        for (int kk = 0; kk < 4; ++kk) kreg[jf * 4 + kk] = *(const bf16x8*)(krow + kk * 32);
      }
    }

    #pragma unroll
    for (int jf = 0; jf < 4; ++jf) {
      int j = j0 + jf * 16 + fr;
      #pragma unroll
      for (int r = 0; r < 4; ++r) {
        float v = s[jf][r] * scale;
        s[jf][r] = (j > i0 + r) ? -1e30f : v;
      }
    }
    float al[4], ls[4];
    #pragma unroll
    for (int r = 0; r < 4; ++r) {
      float mx = fmaxf(fmaxf(s[0][r], s[1][r]), fmaxf(s[2][r], s[3][r]));
      #pragma unroll
      for (int off = 8; off >= 1; off >>= 1) mx = fmaxf(mx, __shfl_xor(mx, off));
      float mn = fmaxf(m_r[r], mx);
      al[r] = __expf(m_r[r] - mn);
      m_r[r] = mn;
      float sum = 0.f;
      #pragma unroll
      for (int jf = 0; jf < 4; ++jf) {
        float p = __expf(s[jf][r] - mn);
        s[jf][r] = p;
        sum += p;
      }
      #pragma unroll
      for (int off = 8; off >= 1; off >>= 1) sum += __shfl_xor(sum, off);
      ls[r] = sum;
    }
    #pragma unroll
    for (int jf = 0; jf < 4; ++jf)
      #pragma unroll
      for (int r = 0; r < 4; ++r)
        Pw[(fq * 4 + r) * 72 + jf * 16 + fr] = f2bf(s[jf][r]);
    #pragma unroll
    for (int r = 0; r < 4; ++r) l_r[r] = l_r[r] * al[r] + ls[r];
    #pragma unroll
    for (int df = 0; df < 8; ++df)
      #pragma unroll
      for (int r = 0; r < 4; ++r) acc[df][r] *= al[r];

    bf16x8 pa0 = *(const bf16x8*)(Pw + fr * 72 + fq * 8);
    bf16x8 pa1 = *(const bf16x8*)(Pw + fr * 72 + 32 + fq * 8);
    #pragma unroll
    for (int df = 0; df < 8; ++df) {
      acc[df] = __builtin_amdgcn_mfma_f32_16x16x32_bf16(pa0, vreg[df * 2],     acc[df], 0, 0, 0);
      acc[df] = __builtin_amdgcn_mfma_f32_16x16x32_bf16(pa1, vreg[df * 2 + 1], acc[df], 0, 0, 0);
    }
  }
  #pragma unroll
  for (int df = 0; df < 8; ++df)
    #pragma unroll
    for (int r = 0; r < 4; ++r) {
      int i = qr0 + fq * 4 + r;
      int d = df * 16 + fr;
      ctx[(size_t)(b * SEQ + i) * DIM + h * DH + d] = f2bf(acc[df][r] / l_r[r]);
    }
}

// ----------------------------------------------------------------- launch ---
extern "C" void kernel_launch(void* const* d_in, const int* in_sizes, int n_in,
                              void* d_out, int out_size, void* d_ws, size_t ws_size,
                              hipStream_t stream) {
  // size-keyed input selection (sizes are pairwise distinct)
  const float *x = nullptr, *gamma = nullptr, *wq = nullptr, *wo = nullptr;
  for (int ii = 0; ii < n_in; ++ii) {
    switch (in_sizes[ii]) {
      case  8388608: x     = (const float*)d_in[ii]; break;
      case     2048: gamma = (const float*)d_in[ii]; break;
      case 12582912: wq    = (const float*)d_in[ii]; break;
      case  4194304: wo    = (const float*)d_in[ii]; break;
    }
  }
  if (!x || !gamma || !wq || !wo) {   // fallback: documented dict order
    x = (const float*)d_in[0]; gamma = (const float*)d_in[1];
    wq = (const float*)d_in[2]; wo = (const float*)d_in[3];
  }

  float* out    = (float*)d_out;           // (2,2048,2048)
  float* cached = out + 8388608;           // (2,2,16,2048,128)

  // ws (134.2 MB, proven footprint):
  //   [0, 33.55MB)      xn (fp32) — dead after QKV GEMM; then reused as:
  //       [0, 16.78MB)      ctx (bf16)
  //       [16.78, 33.55MB)  vT  (bf16)
  //   [33.55, 134.2MB)  qkv (fp32; V third repurposed for packed bf16 q,k)
  // rope table (1 MB) lives in the head of `out`, fully overwritten by the
  // final GEMM — deterministic across replays.
  float* xn   = (float*)d_ws;
  u16*   ctx  = (u16*)d_ws;
  u16*   vT   = ctx + (size_t)ROWS * DIM;
  float* qkvf = (float*)((char*)d_ws + (size_t)ROWS * DIM * 4);
  float2* tab = (float2*)d_out;            // 2048*64*8B = 1 MB scratch

  rms_slow<<<ROWS, 64, 0, stream>>>(x, gamma, xn);
  rope_table<<<131072 / 256, 256, 0, stream>>>(tab);
  gemm_nn<float><<<dim3(ROWS / 128, NQKV / 128), 256, 0, stream>>>(xn, wq, qkvf, ROWS, NQKV, DIM);
  kvout_slow<<<65536, 256, 0, stream>>>(qkvf, cached);
  rope_apply<<<32768, 256, 0, stream>>>(qkvf, tab);
  transpose_v_cast<<<dim3(DH / 32, SEQ / 32, 32), dim3(32, 8), 0, stream>>>(qkvf, vT);
  pack_qk<<<ROWS, 256, 0, stream>>>(qkvf);
  attn_mfma16<<<4096, 64, 0, stream>>>((const u16*)qkvf, vT, ctx);
  gemm_nn<u16><<<dim3(ROWS / 128, DIM / 128), 256, 0, stream>>>(ctx, wo, out, ROWS, DIM, DIM);
}

// Round 12
// 579.774 us; speedup vs baseline: 1.5208x; 1.1698x over previous
//
#include <hip/hip_runtime.h>
#include <cstdint>
#include <cstddef>
#include <math.h>

#define SEQ   2048
#define DIM   2048
#define NQKV  6144
#define NH    16
#define DH    128
#define ROWS  4096   /* b*n */

typedef unsigned short u16;
typedef unsigned int u32;
typedef __attribute__((ext_vector_type(8))) short bf16x8;
typedef __attribute__((ext_vector_type(4))) float f32x4;

__device__ __forceinline__ u16 f2bf(float f) {
  union { float f; u32 u; } v;
  v.f = f;
  u32 r = v.u + 0x7FFFu + ((v.u >> 16) & 1u);
  return (u16)(r >> 16);
}

// ------------------------------------------------ rmsnorm (fp64, 1 wave/row)
// [VERIFIED round 4 — do not touch]
__global__ __launch_bounds__(64) void rms_slow(
    const float* __restrict__ x, const float* __restrict__ g,
    float* __restrict__ xn) {
  int row = blockIdx.x, lane = threadIdx.x;
  const float* xr = x + (size_t)row * DIM;
  double ss = 0.0;
  for (int c = lane; c < DIM; c += 64) { double v = xr[c]; ss += v * v; }
  #pragma unroll
  for (int off = 32; off >= 1; off >>= 1) ss += __shfl_xor(ss, off);
  double nrm = sqrt(ss); if (nrm < 1e-12) nrm = 1e-12;
  double sc = 45.254833995939045 / nrm;   // sqrt(2048)/||x||
  float* dst = xn + (size_t)row * DIM;
  for (int c = lane; c < DIM; c += 64) dst[c] = (float)((double)xr[c] * sc * (double)g[c]);
}

// ----------------------------------------- fp32 -> bf16 cast (8 elems/thread)
__global__ __launch_bounds__(256) void cast_bf16(
    const float* __restrict__ in, u16* __restrict__ out) {
  size_t i = ((size_t)blockIdx.x * 256 + threadIdx.x) * 8;
  float4 f0 = *(const float4*)(in + i);
  float4 f1 = *(const float4*)(in + i + 4);
  union { u16 h[8]; int4 q; } cv;
  cv.h[0]=f2bf(f0.x); cv.h[1]=f2bf(f0.y); cv.h[2]=f2bf(f0.z); cv.h[3]=f2bf(f0.w);
  cv.h[4]=f2bf(f1.x); cv.h[5]=f2bf(f1.y); cv.h[6]=f2bf(f1.z); cv.h[7]=f2bf(f1.w);
  *(int4*)(out + i) = cv.q;
}

// ------------------------------------------------- fp32 -> bf16 transpose ---
// in: R x C fp32 ; out: C x R bf16   (round-0 kernel, logic re-audited)
__global__ void transpose_f32_bf16(const float* __restrict__ in,
                                   u16* __restrict__ out, int R, int C) {
  __shared__ float tile[32][33];
  int bx = blockIdx.x * 32;   // C index
  int by = blockIdx.y * 32;   // R index
  int tx = threadIdx.x, ty = threadIdx.y;   // (32,8)
  #pragma unroll
  for (int j = 0; j < 32; j += 8)
    tile[ty + j][tx] = in[(size_t)(by + ty + j) * C + bx + tx];
  __syncthreads();
  #pragma unroll
  for (int j = 0; j < 32; j += 8)
    out[(size_t)(bx + ty + j) * R + by + tx] = f2bf(tile[tx][ty + j]);
}

// ------------------------------------------ bf16 NT GEMM, XCD-swizzled ------
// C[M,N] = A[M,K] * BT[N,K]^T, fp32 out. 128x128 tile, BK=32, 4 waves.
// MFMA core / fragment reads / C-write byte-identical to the validated
// gemm_nn; staging is now all-int4 (A and BT are pre-cast bf16 row-major).
// Grid is 1-D; decode gives each XCD (wg&7, per round-11-validated mapping)
// ownership of nbn/8 B-column-panels (~3 MB, L2-resident), streaming A.
__global__ __launch_bounds__(256) void gemm_nt(
    const u16* __restrict__ A, const u16* __restrict__ BT,
    float* __restrict__ C, int M, int N, int K) {
  __shared__ u16 As[128 * 40];
  __shared__ u16 Bs[128 * 40];
  int nbn = N >> 7;
  int chunk = nbn >> 3;            // requires nbn % 8 == 0 (48, 16: ok)
  int wg = blockIdx.x;
  int xcd = wg & 7, g = wg >> 3;
  int bm = (g / chunk) * 128;
  int bn = (xcd * chunk + g % chunk) * 128;

  int tid = threadIdx.x;
  int wid = tid >> 6, lane = tid & 63;
  int wr = wid >> 1, wc = wid & 1;
  int fr = lane & 15, fq = lane >> 4;
  int srow = tid >> 2;              // 0..63
  int scol = (tid & 3) * 8;         // bf16 elems, 16B chunk

  f32x4 acc[4][4] = {};

  const u16* a_rd = As + (wr * 64 + fr) * 40 + fq * 8;
  const u16* b_rd = Bs + (wc * 64 + fr) * 40 + fq * 8;

  for (int k0 = 0; k0 < K; k0 += 32) {
    int4 a0 = *(const int4*)(A + (size_t)(bm + srow) * K + k0 + scol);
    int4 a1 = *(const int4*)(A + (size_t)(bm + 64 + srow) * K + k0 + scol);
    int4 b0 = *(const int4*)(BT + (size_t)(bn + srow) * K + k0 + scol);
    int4 b1 = *(const int4*)(BT + (size_t)(bn + 64 + srow) * K + k0 + scol);
    __syncthreads();
    *(int4*)(As + srow * 40 + scol) = a0;
    *(int4*)(As + (64 + srow) * 40 + scol) = a1;
    *(int4*)(Bs + srow * 40 + scol) = b0;
    *(int4*)(Bs + (64 + srow) * 40 + scol) = b1;
    __syncthreads();
    bf16x8 af[4], bfr[4];
    #pragma unroll
    for (int m = 0; m < 4; ++m) af[m]  = *(const bf16x8*)(a_rd + m * 16 * 40);
    #pragma unroll
    for (int n = 0; n < 4; ++n) bfr[n] = *(const bf16x8*)(b_rd + n * 16 * 40);
    #pragma unroll
    for (int m = 0; m < 4; ++m)
      #pragma unroll
      for (int n = 0; n < 4; ++n)
        acc[m][n] = __builtin_amdgcn_mfma_f32_16x16x32_bf16(af[m], bfr[n], acc[m][n], 0, 0, 0);
  }
  #pragma unroll
  for (int m = 0; m < 4; ++m)
    #pragma unroll
    for (int n = 0; n < 4; ++n)
      #pragma unroll
      for (int r = 0; r < 4; ++r) {
        int row = bm + wr * 64 + m * 16 + fq * 4 + r;
        int col = bn + wc * 64 + n * 16 + fr;
        C[(size_t)row * N + col] = acc[m][n][r];
      }
}

// ---------------------------------- cached_kv: one thread per output element
// [VERIFIED round 4 — do not touch]
__global__ __launch_bounds__(256) void kvout_slow(
    const float* __restrict__ qkv, float* __restrict__ cached) {
  size_t gid = (size_t)blockIdx.x * 256 + threadIdx.x;  // 16,777,216
  int d = (int)(gid & 127);
  size_t r = gid >> 7;
  int n = (int)(r & 2047); r >>= 11;
  int h = (int)(r & 15);   r >>= 4;
  int b = (int)(r & 1);    r >>= 1;
  int kv = (int)r;         // 0=k, 1=v  (pre-RoPE)
  cached[gid] = qkv[(size_t)(b * SEQ + n) * NQKV + (size_t)(1 + kv) * DIM + h * DH + d];
}

// ------------------------- RoPE cos/sin table (fp64 build, fp32 store) ------
// [VERIFIED round 10 — unchanged]
__global__ __launch_bounds__(256) void rope_table(float2* __restrict__ tab) {
  int gid = blockIdx.x * 256 + threadIdx.x;   // 131072
  int p = gid & 63;
  int n = gid >> 6;
  double inv = pow(10000.0, -(double)p / 64.0);
  double ang = (double)n * inv;
  tab[gid] = make_float2((float)cos(ang), (float)sin(ang));
}

// ------------------------------------- RoPE apply in-place (fp32, per pair) -
// [VERIFIED round 10 — unchanged]
__global__ __launch_bounds__(256) void rope_apply(float* __restrict__ qkv,
                                                  const float2* __restrict__ tab) {
  int gid = blockIdx.x * 256 + threadIdx.x;   // 8,388,608 pairs (q and k)
  int p = gid & 63;
  int n = (gid >> 6) & 2047;
  int h = (gid >> 17) & 15;
  int s = (gid >> 21) & 1;    // 0 = q, 1 = k
  int b = (gid >> 22) & 1;
  float* base = qkv + (size_t)(b * SEQ + n) * NQKV + s * DIM + h * DH + 2 * p;
  float2 cs = tab[n * 64 + p];
  float2 w = *(float2*)base;
  float2 o;
  o.x = w.x * cs.x - w.y * cs.y;
  o.y = w.y * cs.x + w.x * cs.y;
  *(float2*)base = o;
}

// ------------------------- V transpose + cast -> vT[bh][d][n] (bf16) --------
// [VERIFIED round 6 — unchanged]
__global__ void transpose_v_cast(const float* __restrict__ qkv,
                                 u16* __restrict__ vT) {
  int bh = blockIdx.z; int b = bh >> 4, h = bh & 15;
  int d0 = blockIdx.x * 32, n0 = blockIdx.y * 32;
  __shared__ float tile[32][33];
  int tx = threadIdx.x, ty = threadIdx.y;   // (32,8)
  const float* src = qkv + (size_t)(b * SEQ + n0) * NQKV + 2 * DIM + h * DH + d0;
  #pragma unroll
  for (int j = 0; j < 32; j += 8)
    tile[ty + j][tx] = src[(size_t)(ty + j) * NQKV + tx];
  __syncthreads();
  u16* dst = vT + ((size_t)bh * DH + d0) * SEQ + n0;
  #pragma unroll
  for (int j = 0; j < 32; j += 8)
    dst[(size_t)(ty + j) * SEQ + tx] = f2bf(tile[tx][ty + j]);
}

// ----------------- pack post-RoPE q,k as bf16 into the dead fp32-V region ---
// [VERIFIED round 7 — unchanged]
__global__ __launch_bounds__(256) void pack_qk(float* __restrict__ qkv) {
  int row = blockIdx.x;           // 0..4095
  int t = threadIdx.x;            // 16 elems each over q+k (4096 elems)
  const float* src = qkv + (size_t)row * NQKV + t * 16;
  float4 f0 = ((const float4*)src)[0];
  float4 f1 = ((const float4*)src)[1];
  float4 f2 = ((const float4*)src)[2];
  float4 f3 = ((const float4*)src)[3];
  union { u16 h[16]; int4 q[2]; } cv;
  cv.h[0]=f2bf(f0.x);  cv.h[1]=f2bf(f0.y);  cv.h[2]=f2bf(f0.z);  cv.h[3]=f2bf(f0.w);
  cv.h[4]=f2bf(f1.x);  cv.h[5]=f2bf(f1.y);  cv.h[6]=f2bf(f1.z);  cv.h[7]=f2bf(f1.w);
  cv.h[8]=f2bf(f2.x);  cv.h[9]=f2bf(f2.y);  cv.h[10]=f2bf(f2.z); cv.h[11]=f2bf(f2.w);
  cv.h[12]=f2bf(f3.x); cv.h[13]=f2bf(f3.y); cv.h[14]=f2bf(f3.z); cv.h[15]=f2bf(f3.w);
  u16* dst = (u16*)(qkv + (size_t)row * NQKV) + 8192 + t * 16;
  ((int4*)dst)[0] = cv.q[0];
  ((int4*)dst)[1] = cv.q[1];
}

// --------------------- MFMA causal flash attention, 1 wave / 16 q-rows ------
// [VERIFIED round 11 — byte-identical; XCD-sequential bh ownership]
__global__ __launch_bounds__(64) void attn_mfma16(
    const u16* __restrict__ qkp,   // u16 view of qkvf (packed q,k in V region)
    const u16* __restrict__ vT,    // (32,128,2048) bf16
    u16* __restrict__ ctx) {       // (4096, 2048) bf16
  int wg = blockIdx.x;             // 0..4095
  int xcd = wg & 7;
  int g   = wg >> 3;               // 0..511 within-XCD sequence
  int bh  = (g >> 7) * 8 + xcd;    // 0..31
  int qt  = 127 - (g & 127);       // longest blocks first within each bh
  int b = bh >> 4, h = bh & 15;
  int lane = threadIdx.x;
  int fr = lane & 15, fq = lane >> 4;
  int qr0 = qt * 16;

  __shared__ u16 Pw[16 * 72];

  const size_t rstr = 2 * NQKV;    // u16 per row
  const u16* Qb = qkp + (size_t)(b * SEQ) * rstr + 8192 + h * 128;
  const u16* Kb = qkp + (size_t)(b * SEQ) * rstr + 10240 + h * 128;
  const u16* Vt = vT + (size_t)bh * DH * SEQ;

  bf16x8 qf[4];
  {
    const u16* qrow = Qb + (size_t)(qr0 + fr) * rstr + fq * 8;
    #pragma unroll
    for (int kk = 0; kk < 4; ++kk) qf[kk] = *(const bf16x8*)(qrow + kk * 32);
  }

  f32x4 acc[8] = {};
  float m_r[4], l_r[4];
  #pragma unroll
  for (int r = 0; r < 4; ++r) { m_r[r] = -3e38f; l_r[r] = 0.f; }

  const float scale = 0.08838834764831845f;
  int i0 = qr0 + fq * 4;
  int jt_end = qt >> 2;

  bf16x8 kreg[16];   // [jf][kk]
  bf16x8 vreg[16];   // [df][half]

  #pragma unroll
  for (int jf = 0; jf < 4; ++jf) {
    const u16* krow = Kb + (size_t)(jf * 16 + fr) * rstr + fq * 8;
    #pragma unroll
    for (int kk = 0; kk < 4; ++kk) kreg[jf * 4 + kk] = *(const bf16x8*)(krow + kk * 32);
  }

  for (int jt = 0; jt <= jt_end; ++jt) {
    int j0 = jt * 64;

    #pragma unroll
    for (int df = 0; df < 8; ++df) {
      const u16* vrow = Vt + (size_t)(df * 16 + fr) * SEQ + j0 + fq * 8;
      vreg[df * 2]     = *(const bf16x8*)(vrow);
      vreg[df * 2 + 1] = *(const bf16x8*)(vrow + 32);
    }

    f32x4 s[4];
    #pragma unroll
    for (int jf = 0; jf < 4; ++jf) {
      f32x4 sa = {0.f, 0.f, 0.f, 0.f};
      #pragma unroll
      for (int kk = 0; kk < 4; ++kk)
        sa = __builtin_amdgcn_mfma_f32_16x16x32_bf16(qf[kk], kreg[jf * 4 + kk], sa, 0, 0, 0);
      s[jf] = sa;
    }

    if (jt < jt_end) {
      int jn0 = j0 + 64;
      #pragma unroll
      for (int jf = 0; jf < 4; ++jf) {
        const u16* krow = Kb + (size_t)(jn0 + jf * 16 + fr) * rstr + fq * 8;
        #pragma unroll
        for (int kk = 0; kk < 4; ++kk) kreg[jf * 4 + kk] = *(const bf16x8*)(krow + kk * 32);
      }
    }

    #pragma unroll
    for (int jf = 0; jf < 4; ++jf) {
      int j = j0 + jf * 16 + fr;
      #pragma unroll
      for (int r = 0; r < 4; ++r) {
        float v = s[jf][r] * scale;
        s[jf][r] = (j > i0 + r) ? -1e30f : v;
      }
    }
    float al[4], ls[4];
    #pragma unroll
    for (int r = 0; r < 4; ++r) {
      float mx = fmaxf(fmaxf(s[0][r], s[1][r]), fmaxf(s[2][r], s[3][r]));
      #pragma unroll
      for (int off = 8; off >= 1; off >>= 1) mx = fmaxf(mx, __shfl_xor(mx, off));
      float mn = fmaxf(m_r[r], mx);
      al[r] = __expf(m_r[r] - mn);
      m_r[r] = mn;
      float sum = 0.f;
      #pragma unroll
      for (int jf = 0; jf < 4; ++jf) {
        float p = __expf(s[jf][r] - mn);
        s[jf][r] = p;
        sum += p;
      }
      #pragma unroll
      for (int off = 8; off >= 1; off >>= 1) sum += __shfl_xor(sum, off);
      ls[r] = sum;
    }
    #pragma unroll
    for (int jf = 0; jf < 4; ++jf)
      #pragma unroll
      for (int r = 0; r < 4; ++r)
        Pw[(fq * 4 + r) * 72 + jf * 16 + fr] = f2bf(s[jf][r]);
    #pragma unroll
    for (int r = 0; r < 4; ++r) l_r[r] = l_r[r] * al[r] + ls[r];
    #pragma unroll
    for (int df = 0; df < 8; ++df)
      #pragma unroll
      for (int r = 0; r < 4; ++r) acc[df][r] *= al[r];

    bf16x8 pa0 = *(const bf16x8*)(Pw + fr * 72 + fq * 8);
    bf16x8 pa1 = *(const bf16x8*)(Pw + fr * 72 + 32 + fq * 8);
    #pragma unroll
    for (int df = 0; df < 8; ++df) {
      acc[df] = __builtin_amdgcn_mfma_f32_16x16x32_bf16(pa0, vreg[df * 2],     acc[df], 0, 0, 0);
      acc[df] = __builtin_amdgcn_mfma_f32_16x16x32_bf16(pa1, vreg[df * 2 + 1], acc[df], 0, 0, 0);
    }
  }
  #pragma unroll
  for (int df = 0; df < 8; ++df)
    #pragma unroll
    for (int r = 0; r < 4; ++r) {
      int i = qr0 + fq * 4 + r;
      int d = df * 16 + fr;
      ctx[(size_t)(b * SEQ + i) * DIM + h * DH + d] = f2bf(acc[df][r] / l_r[r]);
    }
}

// ----------------------------------------------------------------- launch ---
extern "C" void kernel_launch(void* const* d_in, const int* in_sizes, int n_in,
                              void* d_out, int out_size, void* d_ws, size_t ws_size,
                              hipStream_t stream) {
  // size-keyed input selection (sizes are pairwise distinct)
  const float *x = nullptr, *gamma = nullptr, *wq = nullptr, *wo = nullptr;
  for (int ii = 0; ii < n_in; ++ii) {
    switch (in_sizes[ii]) {
      case  8388608: x     = (const float*)d_in[ii]; break;
      case     2048: gamma = (const float*)d_in[ii]; break;
      case 12582912: wq    = (const float*)d_in[ii]; break;
      case  4194304: wo    = (const float*)d_in[ii]; break;
    }
  }
  if (!x || !gamma || !wq || !wo) {   // fallback: documented dict order
    x = (const float*)d_in[0]; gamma = (const float*)d_in[1];
    wq = (const float*)d_in[2]; wo = (const float*)d_in[3];
  }

  float* out    = (float*)d_out;           // (2,2048,2048) = first 33.55 MB
  float* cached = out + 8388608;           // (2,2,16,2048,128) at byte 33.55M

  // ws (134.2 MB, proven footprint), time-multiplexed:
  //   [0, 25.2M)       xn(head) -> wqkvT -> ctx(first 16.8M)
  //   [25.2M, 33.55M)  xn(tail) -> woutT (live until final GEMM)
  //   [33.55M, 134.2M) qkvf (fp32; V third repurposed for packed bf16 q,k)
  // out-region scratch (dead before final GEMM writes out):
  //   out[0, 16.8M)    xnb (bf16 A) -> vT (bf16) after QKV GEMM
  //   out[16.8M,17.8M) rope table
  float* xn    = (float*)d_ws;
  u16*   wqkvT = (u16*)d_ws;
  u16*   ctx   = (u16*)d_ws;
  u16*   woutT = (u16*)((char*)d_ws + 25165824);
  float* qkvf  = (float*)((char*)d_ws + 33554432);
  u16*   xnb   = (u16*)d_out;
  u16*   vT    = (u16*)d_out;
  float2* tab  = (float2*)((char*)d_out + 16777216);

  rms_slow<<<ROWS, 64, 0, stream>>>(x, gamma, xn);
  rope_table<<<131072 / 256, 256, 0, stream>>>(tab);
  cast_bf16<<<4096, 256, 0, stream>>>(xn, xnb);                 // xn dead after
  transpose_f32_bf16<<<dim3(NQKV / 32, DIM / 32), dim3(32, 8), 0, stream>>>(wq, wqkvT, DIM, NQKV);
  transpose_f32_bf16<<<dim3(DIM / 32, DIM / 32), dim3(32, 8), 0, stream>>>(wo, woutT, DIM, DIM);
  gemm_nt<<<(ROWS / 128) * (NQKV / 128), 256, 0, stream>>>(xnb, wqkvT, qkvf, ROWS, NQKV, DIM);
  kvout_slow<<<65536, 256, 0, stream>>>(qkvf, cached);
  rope_apply<<<32768, 256, 0, stream>>>(qkvf, tab);
  transpose_v_cast<<<dim3(DH / 32, SEQ / 32, 32), dim3(32, 8), 0, stream>>>(qkvf, vT);  // overwrites dead xnb
  pack_qk<<<ROWS, 256, 0, stream>>>(qkvf);
  attn_mfma16<<<4096, 64, 0, stream>>>((const u16*)qkvf, vT, ctx);   // ctx overwrites dead wqkvT
  gemm_nt<<<(ROWS / 128) * (DIM / 128), 256, 0, stream>>>(ctx, woutT, out, ROWS, DIM, DIM);
}